// Round 2
// baseline (5905.487 us; speedup 1.0000x reference)
//
#include <hip/hip_runtime.h>
#include <math.h>

#define TF 40
#define TE 64
#define NTH 256

__global__ __launch_bounds__(NTH, 3)
void autoint_fused(const float* __restrict__ x,
                   const float* __restrict__ Wq, const float* __restrict__ bq,
                   const float* __restrict__ Wk, const float* __restrict__ bk,
                   const float* __restrict__ Wv, const float* __restrict__ bv,
                   const float* __restrict__ Wr, const float* __restrict__ br,
                   const float* __restrict__ gamma, const float* __restrict__ beta,
                   float* __restrict__ out)
{
    // sU: cur activations [40][64] (2560 f32) UNION scores [2][40][40] (3200 f32)
    __shared__ float sU[2 * TF * TF];
    __shared__ float sq[TF][TE];
    __shared__ float sk[TF][TE + 1];   // +1 pad: P2 reads per-lane rows (stride 64 would be 32-way conflict)
    __shared__ float sv[TF][TE];
    __shared__ float sres[TF][TE];

    const int t    = threadIdx.x;
    const int wave = t >> 6;
    const int lane = t & 63;
    const int e    = lane;
    const size_t base = (size_t)blockIdx.x * (TF * TE);

    // ---- wave-specialized weight column: W[:, e] in 64 VGPRs, loaded ONCE ----
    const float* __restrict__ Wsel =
        (wave == 0) ? Wq : (wave == 1) ? Wk : (wave == 2) ? Wv : Wr;
    const float bsel =
        (wave == 0) ? bq[e] : (wave == 1) ? bk[e] : (wave == 2) ? bv[e] : br[e];
    float* const dst     = (wave == 0) ? &sq[0][0] : (wave == 1) ? &sk[0][0]
                         : (wave == 2) ? &sv[0][0] : &sres[0][0];
    const int    dstride = (wave == 1) ? (TE + 1) : TE;

    float wcol[TE];
    #pragma unroll
    for (int c = 0; c < TE; ++c) wcol[c] = Wsel[c * TE + e];

    const float gv = gamma[e], btv = beta[e];

    // load x tile into cur (coalesced float4)
    {
        const float4* xb4 = (const float4*)(x + base);
        float4* s4 = (float4*)sU;
        for (int i = t; i < TF * TE / 4; i += NTH) s4[i] = xb4[i];
    }
    __syncthreads();

    for (int lay = 0; lay < 2; ++lay) {
        // ---------- P1: dst = relu(cur @ Wsel + bsel), wave m owns matrix m ----------
        #pragma unroll 1
        for (int fg = 0; fg < TF; fg += 8) {
            float acc[8];
            #pragma unroll
            for (int r = 0; r < 8; ++r) acc[r] = 0.f;
            #pragma unroll
            for (int c = 0; c < TE; c += 4) {
                #pragma unroll
                for (int r = 0; r < 8; ++r) {
                    const float4 xv = *(const float4*)&sU[(fg + r) * TE + c];  // wave-uniform broadcast
                    acc[r] = fmaf(xv.x, wcol[c + 0], acc[r]);
                    acc[r] = fmaf(xv.y, wcol[c + 1], acc[r]);
                    acc[r] = fmaf(xv.z, wcol[c + 2], acc[r]);
                    acc[r] = fmaf(xv.w, wcol[c + 3], acc[r]);
                }
            }
            #pragma unroll
            for (int r = 0; r < 8; ++r)
                dst[(fg + r) * dstride + e] = fmaxf(acc[r] + bsel, 0.f);
        }
        __syncthreads();   // sq/sk/sv/sres visible; cur reads done -> scores may overwrite sU

        // ---------- P2: S = qh @ khT / sqrt(32), softmax over g ----------
        {
            const int h = wave >> 1;
            const int fbase = (wave & 1) * 20;
            const int g = lane;
            const int gg = (g < TF) ? g : 0;
            for (int j = 0; j < 20; ++j) {
                const int f = fbase + j;
                float s = 0.f;
                #pragma unroll
                for (int d = 0; d < 32; d += 4) {
                    const float4 qv = *(const float4*)&sq[f][32 * h + d];   // wave-uniform broadcast
                    const float4 kv = *(const float4*)&sk[gg][32 * h + d];  // per-lane row, padded stride
                    s = fmaf(qv.x, kv.x, s); s = fmaf(qv.y, kv.y, s);
                    s = fmaf(qv.z, kv.z, s); s = fmaf(qv.w, kv.w, s);
                }
                s *= 0.17677669529663687f;   // 1/sqrt(32)
                if (g >= TF) s = -INFINITY;
                float m = s;
                #pragma unroll
                for (int off = 32; off; off >>= 1) m = fmaxf(m, __shfl_xor(m, off));
                const float p = __expf(s - m);   // invalid lanes -> 0
                float sum = p;
                #pragma unroll
                for (int off = 32; off; off >>= 1) sum += __shfl_xor(sum, off);
                const float inv = 1.0f / sum;
                if (g < TF) sU[h * (TF * TF) + f * TF + g] = p * inv;
            }
        }
        __syncthreads();   // scores visible

        // ---------- P3: O = S @ vh, merge heads, + res, relu ----------
        float vo[10];
        {
            const int h = e >> 5;
            const float* ssrow = &sU[h * (TF * TF)];
            #pragma unroll
            for (int i = 0; i < 10; ++i) vo[i] = 0.f;
            for (int g = 0; g < TF; g += 4) {
                const float v0 = sv[g + 0][e];
                const float v1 = sv[g + 1][e];
                const float v2 = sv[g + 2][e];
                const float v3 = sv[g + 3][e];
                #pragma unroll
                for (int i = 0; i < 10; ++i) {
                    const int f = wave + 4 * i;
                    const float4 sw = *(const float4*)&ssrow[f * TF + g];   // 2-addr broadcast (h split: free)
                    vo[i] = fmaf(sw.x, v0, vo[i]); vo[i] = fmaf(sw.y, v1, vo[i]);
                    vo[i] = fmaf(sw.z, v2, vo[i]); vo[i] = fmaf(sw.w, v3, vo[i]);
                }
            }
            #pragma unroll
            for (int i = 0; i < 10; ++i) {
                const int f = wave + 4 * i;
                vo[i] = fmaxf(vo[i] + sres[f][e], 0.f);
            }
        }
        __syncthreads();   // all score reads done before sU becomes next-layer cur

        // ---------- P4: LayerNorm over e ----------
        #pragma unroll
        for (int i = 0; i < 10; ++i) {
            const int f = wave + 4 * i;
            const float val = vo[i];
            float s1 = val, s2 = val * val;
            #pragma unroll
            for (int off = 32; off; off >>= 1) {
                s1 += __shfl_xor(s1, off);
                s2 += __shfl_xor(s2, off);
            }
            const float mu  = s1 * (1.0f / 64.0f);
            const float var = s2 * (1.0f / 64.0f) - mu * mu;
            const float y = (val - mu) * rsqrtf(var + 1e-3f) * gv + btv;
            if (lay == 0) sU[f * TE + e] = y;
            else          out[base + f * TE + e] = y;
        }
        if (lay == 0) __syncthreads();
    }
}

extern "C" void kernel_launch(void* const* d_in, const int* in_sizes, int n_in,
                              void* d_out, int out_size, void* d_ws, size_t ws_size,
                              hipStream_t stream) {
    const float* x     = (const float*)d_in[0];
    const float* Wq    = (const float*)d_in[1];
    const float* bq    = (const float*)d_in[2];
    const float* Wk    = (const float*)d_in[3];
    const float* bk    = (const float*)d_in[4];
    const float* Wv    = (const float*)d_in[5];
    const float* bv    = (const float*)d_in[6];
    const float* Wr    = (const float*)d_in[7];
    const float* br    = (const float*)d_in[8];
    const float* gamma = (const float*)d_in[9];
    const float* beta  = (const float*)d_in[10];
    float* outp = (float*)d_out;

    const int B = in_sizes[0] / (TF * TE);
    autoint_fused<<<B, NTH, 0, stream>>>(x, Wq, bq, Wk, bk, Wv, bv, Wr, br, gamma, beta, outp);
}

// Round 3
// 3309.396 us; speedup vs baseline: 1.7845x; 1.7845x over previous
//
#include <hip/hip_runtime.h>
#include <math.h>

#define TF 40
#define TE 64
#define NTH 256

__global__ __launch_bounds__(NTH, 4)
void autoint_fused(const float* __restrict__ x,
                   const float* __restrict__ Wq, const float* __restrict__ bq,
                   const float* __restrict__ Wk, const float* __restrict__ bk,
                   const float* __restrict__ Wv, const float* __restrict__ bv,
                   const float* __restrict__ Wr, const float* __restrict__ br,
                   const float* __restrict__ gamma, const float* __restrict__ beta,
                   float* __restrict__ out)
{
    // sU: cur activations [40][64] (2560 f32) UNION scores [2][40][40] (3200 f32)
    __shared__ float sU[2 * TF * TF];
    __shared__ float sq[TF][TE];
    __shared__ float sk[TF][TE + 1];   // +1 pad: P2 kr-load reads per-lane rows
    __shared__ float sv[TF][TE];

    const int t    = threadIdx.x;
    const int wave = t >> 6;
    const int lane = t & 63;
    const int e    = lane;
    const size_t base = (size_t)blockIdx.x * (TF * TE);

    const float bqv = bq[e], bkv = bk[e], bvv = bv[e], brv = br[e];
    const float gv = gamma[e], btv = beta[e];

    // load x tile into cur (coalesced float4)
    {
        const float4* xb4 = (const float4*)(x + base);
        float4* s4 = (float4*)sU;
        for (int i = t; i < TF * TE / 4; i += NTH) s4[i] = xb4[i];
    }
    __syncthreads();

    float res_reg[10];

    for (int lay = 0; lay < 2; ++lay) {
        // ---------- P1: q,k,v,res = relu(cur @ W + b) ----------
        // wave owns rows f = wave + 4*i (i<10); lane owns output column e.
        // Each b128 broadcast of cur feeds 16 FMAs (4 matrices x 4 c) -> LDS pipe stays cold.
        float acc[4][10];
        #pragma unroll
        for (int m = 0; m < 4; ++m)
            #pragma unroll
            for (int i = 0; i < 10; ++i) acc[m][i] = 0.f;

        #pragma unroll 2
        for (int c = 0; c < TE; c += 4) {
            float w[4][4];
            #pragma unroll
            for (int j = 0; j < 4; ++j) {
                w[0][j] = Wq[(c + j) * TE + e];   // coalesced dword, L1/L2-resident
                w[1][j] = Wk[(c + j) * TE + e];
                w[2][j] = Wv[(c + j) * TE + e];
                w[3][j] = Wr[(c + j) * TE + e];
            }
            #pragma unroll
            for (int i = 0; i < 10; ++i) {
                const float4 xv = *(const float4*)&sU[(wave + 4 * i) * TE + c];  // wave-uniform broadcast
                #pragma unroll
                for (int m = 0; m < 4; ++m) {
                    acc[m][i] = fmaf(xv.x, w[m][0], acc[m][i]);
                    acc[m][i] = fmaf(xv.y, w[m][1], acc[m][i]);
                    acc[m][i] = fmaf(xv.z, w[m][2], acc[m][i]);
                    acc[m][i] = fmaf(xv.w, w[m][3], acc[m][i]);
                }
            }
        }
        #pragma unroll
        for (int i = 0; i < 10; ++i) {
            const int f = wave + 4 * i;
            sq[f][e]   = fmaxf(acc[0][i] + bqv, 0.f);
            sk[f][e]   = fmaxf(acc[1][i] + bkv, 0.f);
            sv[f][e]   = fmaxf(acc[2][i] + bvv, 0.f);
            res_reg[i] = fmaxf(acc[3][i] + brv, 0.f);
        }
        __syncthreads();   // sq/sk/sv visible; cur reads done -> scores may overwrite sU

        // ---------- P2: S = qh @ khT / sqrt(32), softmax over g ----------
        // wave -> (h = wave>>1, f = (wave&1)*20 + j), lane = g.
        // K row hoisted to 8 float4 regs once per layer (saves 160 b128 reads/wave).
        {
            const int h = wave >> 1;
            const int fbase = (wave & 1) * 20;
            const int g = lane;
            const int gg = (g < TF) ? g : 0;
            float4 kr[8];
            #pragma unroll
            for (int dd = 0; dd < 8; ++dd)
                kr[dd] = *(const float4*)&sk[gg][32 * h + 4 * dd];
            for (int j = 0; j < 20; ++j) {
                const int f = fbase + j;
                float s = 0.f;
                #pragma unroll
                for (int dd = 0; dd < 8; ++dd) {
                    const float4 qv = *(const float4*)&sq[f][32 * h + 4 * dd];  // broadcast
                    s = fmaf(qv.x, kr[dd].x, s); s = fmaf(qv.y, kr[dd].y, s);
                    s = fmaf(qv.z, kr[dd].z, s); s = fmaf(qv.w, kr[dd].w, s);
                }
                s *= 0.17677669529663687f;   // 1/sqrt(32)
                if (g >= TF) s = -INFINITY;
                float m = s;
                #pragma unroll
                for (int off = 32; off; off >>= 1) m = fmaxf(m, __shfl_xor(m, off));
                const float p = __expf(s - m);   // invalid lanes -> 0
                float sum = p;
                #pragma unroll
                for (int off = 32; off; off >>= 1) sum += __shfl_xor(sum, off);
                const float inv = 1.0f / sum;
                if (g < TF) sU[h * (TF * TF) + f * TF + g] = p * inv;
            }
        }
        __syncthreads();   // scores visible

        // ---------- P3: O = S @ vh, merge heads, + res, relu ----------
        float vo[10];
        {
            const int h = e >> 5;
            const float* ssrow = &sU[h * (TF * TF)];
            #pragma unroll
            for (int i = 0; i < 10; ++i) vo[i] = 0.f;
            for (int g = 0; g < TF; g += 4) {
                const float v0 = sv[g + 0][e];
                const float v1 = sv[g + 1][e];
                const float v2 = sv[g + 2][e];
                const float v3 = sv[g + 3][e];
                #pragma unroll
                for (int i = 0; i < 10; ++i) {
                    const int f = wave + 4 * i;
                    const float4 sw = *(const float4*)&ssrow[f * TF + g];   // 2-addr broadcast (free)
                    vo[i] = fmaf(sw.x, v0, vo[i]); vo[i] = fmaf(sw.y, v1, vo[i]);
                    vo[i] = fmaf(sw.z, v2, vo[i]); vo[i] = fmaf(sw.w, v3, vo[i]);
                }
            }
            #pragma unroll
            for (int i = 0; i < 10; ++i) vo[i] = fmaxf(vo[i] + res_reg[i], 0.f);
        }
        __syncthreads();   // all score reads done before sU becomes next-layer cur

        // ---------- P4: LayerNorm over e ----------
        #pragma unroll
        for (int i = 0; i < 10; ++i) {
            const int f = wave + 4 * i;
            const float val = vo[i];
            float s1 = val, s2 = val * val;
            #pragma unroll
            for (int off = 32; off; off >>= 1) {
                s1 += __shfl_xor(s1, off);
                s2 += __shfl_xor(s2, off);
            }
            const float mu  = s1 * (1.0f / 64.0f);
            const float var = s2 * (1.0f / 64.0f) - mu * mu;
            const float y = (val - mu) * rsqrtf(var + 1e-3f) * gv + btv;
            if (lay == 0) sU[f * TE + e] = y;
            else          out[base + f * TE + e] = y;
        }
        if (lay == 0) __syncthreads();
    }
}

extern "C" void kernel_launch(void* const* d_in, const int* in_sizes, int n_in,
                              void* d_out, int out_size, void* d_ws, size_t ws_size,
                              hipStream_t stream) {
    const float* x     = (const float*)d_in[0];
    const float* Wq    = (const float*)d_in[1];
    const float* bq    = (const float*)d_in[2];
    const float* Wk    = (const float*)d_in[3];
    const float* bk    = (const float*)d_in[4];
    const float* Wv    = (const float*)d_in[5];
    const float* bv    = (const float*)d_in[6];
    const float* Wr    = (const float*)d_in[7];
    const float* br    = (const float*)d_in[8];
    const float* gamma = (const float*)d_in[9];
    const float* beta  = (const float*)d_in[10];
    float* outp = (float*)d_out;

    const int B = in_sizes[0] / (TF * TE);
    autoint_fused<<<B, NTH, 0, stream>>>(x, Wq, bq, Wk, bk, Wv, bv, Wr, br, gamma, beta, outp);
}

// Round 4
// 826.698 us; speedup vs baseline: 7.1435x; 4.0032x over previous
//
#include <hip/hip_runtime.h>
#include <math.h>

#define TF 40
#define FP 48            // padded f rows
#define TE 64
#define RS 72            // row stride in bf16 elems: 144B, 16B-aligned, bank-uniform
#define NTH 256
#define CURSZ (FP * RS)  // 3456

typedef __attribute__((ext_vector_type(8))) short bf16x8;
typedef __attribute__((ext_vector_type(4))) float f32x4;
typedef unsigned int uint;
typedef unsigned short ushort;

#define MFMA(a, b, c) __builtin_amdgcn_mfma_f32_16x16x32_bf16(a, b, c, 0, 0, 0)

__device__ __forceinline__ ushort f2bf(float x) {          // RNE
    union { float f; uint u; } a; a.f = x;
    uint r = a.u + 0x7FFFu + ((a.u >> 16) & 1u);
    return (ushort)(r >> 16);
}
__device__ __forceinline__ float bf2f(ushort h) {
    union { uint u; float f; } a; a.u = ((uint)h) << 16;
    return a.f;
}

// ---- prep: pre-swizzle W into MFMA B-fragment order in d_ws ----
// layout: frag_id = ((mat*2 + k2)*4 + etile); elem = frag_id*512 + lane*8 + j
// value  = W[k2*32 + (lane>>4)*8 + j][etile*16 + (lane&15)]  (bf16 RNE)
__global__ void prep_wfrags(const float* __restrict__ Wq, const float* __restrict__ Wk,
                            const float* __restrict__ Wv, const float* __restrict__ Wr,
                            ushort* __restrict__ wsf) {
    int idx = blockIdx.x * blockDim.x + threadIdx.x;   // 16384 total
    int j    = idx & 7;
    int lane = (idx >> 3) & 63;
    int et   = (idx >> 9) & 3;
    int k2   = (idx >> 11) & 1;
    int mat  = (idx >> 12) & 3;
    const float* W = (mat == 0) ? Wq : (mat == 1) ? Wk : (mat == 2) ? Wv : Wr;
    int k = k2 * 32 + (lane >> 4) * 8 + j;
    int e = et * 16 + (lane & 15);
    wsf[idx] = f2bf(W[k * TE + e]);
}

__global__ __launch_bounds__(NTH)
void autoint_mfma(const float* __restrict__ x,
                  const float* __restrict__ bq, const float* __restrict__ bk,
                  const float* __restrict__ bv, const float* __restrict__ br,
                  const float* __restrict__ gamma, const float* __restrict__ beta,
                  const ushort* __restrict__ wsf,
                  float* __restrict__ out) {
    // cur hi/lo [48][72] bf16; after P1 reads, aliased as P[head0]/P[head1]
    __shared__ ushort sCur[2][CURSZ];
    __shared__ ushort sQ[CURSZ];          // q [48][72] bf16 row-major [f][d]
    __shared__ ushort sK[CURSZ];          // k [48][72]
    __shared__ ushort sVT[TE * RS];       // v transposed [e=64][g(48,pad 72)]
    __shared__ float  sRed[2][4][FP];     // LN partials: sum, sumsq per wave

    const int t  = threadIdx.x;
    const int w  = t >> 6;                // wave 0..3 = e-tile
    const int l  = t & 63;
    const int r0 = l & 15;
    const int kg = l >> 4;
    const int ec = 16 * w + r0;           // this lane's output column (C-frag col)
    const size_t base = (size_t)blockIdx.x * (TF * TE);

    const float bQ = bq[ec], bK = bk[ec], bV = bv[ec], bR = br[ec];
    const float gV = gamma[ec], btV = beta[ec];

    // ---- W B-fragments: 8 x bf16x8 in regs, loaded once, reused both layers ----
    const bf16x8* wsv = (const bf16x8*)wsf;
    const bf16x8 wq0 = wsv[((0*2+0)*4 + w)*64 + l], wq1 = wsv[((0*2+1)*4 + w)*64 + l];
    const bf16x8 wk0 = wsv[((1*2+0)*4 + w)*64 + l], wk1 = wsv[((1*2+1)*4 + w)*64 + l];
    const bf16x8 wv0 = wsv[((2*2+0)*4 + w)*64 + l], wv1 = wsv[((2*2+1)*4 + w)*64 + l];
    const bf16x8 wr0 = wsv[((3*2+0)*4 + w)*64 + l], wr1 = wsv[((3*2+1)*4 + w)*64 + l];

    // ---- load x, split hi/lo bf16 into cur ----
    {
        const float4* xb4 = (const float4*)(x + base);
        for (int i = t; i < TF * TE / 4; i += NTH) {     // 640
            float4 xv = xb4[i];
            int f = i >> 4, c = (i & 15) << 2;
            ushort h0 = f2bf(xv.x), h1 = f2bf(xv.y), h2 = f2bf(xv.z), h3 = f2bf(xv.w);
            uint2 ph; ph.x = h0 | ((uint)h1 << 16); ph.y = h2 | ((uint)h3 << 16);
            *(uint2*)&sCur[0][f * RS + c] = ph;
            ushort l0 = f2bf(xv.x - bf2f(h0)), l1 = f2bf(xv.y - bf2f(h1));
            ushort l2 = f2bf(xv.z - bf2f(h2)), l3 = f2bf(xv.w - bf2f(h3));
            uint2 pl; pl.x = l0 | ((uint)l1 << 16); pl.y = l2 | ((uint)l3 << 16);
            *(uint2*)&sCur[1][f * RS + c] = pl;
        }
        // zero pad rows 40..47 of cur (hi+lo): 2*8*36 uints
        for (int i = t; i < 576; i += NTH) {
            int part = i / 288, rem = i - part * 288;
            int row = 40 + rem / 36, c = rem % 36;
            ((uint*)&sCur[part][0])[row * 36 + c] = 0u;
        }
        // zero sVT cols 48..71 (uints 24..35) all 64 rows: finite-safe k-dim pad
        for (int i = t; i < 768; i += NTH) {
            int row = i / 12, c = i % 12;
            ((uint*)&sVT[0])[row * 36 + 24 + c] = 0u;
        }
    }
    __syncthreads();   // B0

    for (int lay = 0; lay < 2; ++lay) {
        // ================= P1: q,k,v,res = relu(cur @ W + b)  (MFMA) =================
        // A = cur (hi+lo split), B = W_hi frags; wave w owns e-tile w for all 4 mats.
        f32x4 res0, res1, res2;
        #pragma unroll
        for (int ft = 0; ft < 3; ++ft) {
            const int rowb = (ft * 16 + r0) * RS + kg * 8;
            bf16x8 ah0 = *(const bf16x8*)&sCur[0][rowb];
            bf16x8 ah1 = *(const bf16x8*)&sCur[0][rowb + 32];
            bf16x8 al0 = *(const bf16x8*)&sCur[1][rowb];
            bf16x8 al1 = *(const bf16x8*)&sCur[1][rowb + 32];
            f32x4 z = {0.f, 0.f, 0.f, 0.f};
            f32x4 aq = z, ak = z, av = z, ar = z;
            aq = MFMA(ah0, wq0, aq); aq = MFMA(ah1, wq1, aq);
            aq = MFMA(al0, wq0, aq); aq = MFMA(al1, wq1, aq);
            ak = MFMA(ah0, wk0, ak); ak = MFMA(ah1, wk1, ak);
            ak = MFMA(al0, wk0, ak); ak = MFMA(al1, wk1, ak);
            av = MFMA(ah0, wv0, av); av = MFMA(ah1, wv1, av);
            av = MFMA(al0, wv0, av); av = MFMA(al1, wv1, av);
            ar = MFMA(ah0, wr0, ar); ar = MFMA(ah1, wr1, ar);
            ar = MFMA(al0, wr0, ar); ar = MFMA(al1, wr1, ar);
            // epilogue: bias + relu; C-frag row = ft*16 + 4*kg + r, col = ec
            ushort pv[4];
            f32x4 rr;
            #pragma unroll
            for (int r = 0; r < 4; ++r) {
                const int fr = ft * 16 + 4 * kg + r;
                sQ[fr * RS + ec] = f2bf(fmaxf(aq[r] + bQ, 0.f));
                sK[fr * RS + ec] = f2bf(fmaxf(ak[r] + bK, 0.f));
                pv[r] = f2bf(fmaxf(av[r] + bV, 0.f));
                rr[r] = fmaxf(ar[r] + bR, 0.f);
            }
            uint2 pk; pk.x = pv[0] | ((uint)pv[1] << 16); pk.y = pv[2] | ((uint)pv[3] << 16);
            *(uint2*)&sVT[ec * RS + ft * 16 + 4 * kg] = pk;   // v transposed: [e][f]
            if (ft == 0) res0 = rr; else if (ft == 1) res1 = rr; else res2 = rr;
        }
        __syncthreads();   // B1: q/k/vT ready; cur A-reads done -> P may overwrite

        // zero P cols 48..63, rows 0..47, both heads (k-dim pad for P3 kstep2)
        for (int i = t; i < 768; i += NTH) {
            int ph = i / 384, rem = i - ph * 384;
            int row = rem >> 3, c = rem & 7;
            ((uint*)&sCur[ph][0])[row * 36 + 24 + c] = 0u;
        }

        // ================= P2: S = q k^T / sqrt(32), softmax -> P (bf16) =================
        // unit u in 0..5: head h = u/3, ftile ft = u%3. waves: {w} + {w+4 if w<2}.
        auto p2unit = [&](int u) {
            const int h  = (u >= 3) ? 1 : 0;
            const int ft = u - 3 * h;
            const int co = 32 * h + kg * 8;
            bf16x8 a  = *(const bf16x8*)&sQ[(ft * 16 + r0) * RS + co];
            bf16x8 b0 = *(const bf16x8*)&sK[(r0) * RS + co];
            bf16x8 b1 = *(const bf16x8*)&sK[(16 + r0) * RS + co];
            bf16x8 b2 = *(const bf16x8*)&sK[(32 + r0) * RS + co];
            f32x4 z = {0.f, 0.f, 0.f, 0.f};
            f32x4 c0 = MFMA(a, b0, z);
            f32x4 c1 = MFMA(a, b1, z);
            f32x4 c2 = MFMA(a, b2, z);
            ushort* Ph = &sCur[h][0];
            #pragma unroll
            for (int r = 0; r < 4; ++r) {
                const float SC = 0.17677669529663687f;
                float v0 = c0[r] * SC, v1 = c1[r] * SC;
                float v2 = (r0 < 8) ? c2[r] * SC : -3.0e38f;   // cols 40..47 masked
                float m = fmaxf(fmaxf(v0, v1), v2);
                m = fmaxf(m, __shfl_xor(m, 1)); m = fmaxf(m, __shfl_xor(m, 2));
                m = fmaxf(m, __shfl_xor(m, 4)); m = fmaxf(m, __shfl_xor(m, 8));
                float p0 = exp2f((v0 - m) * 1.44269504f);
                float p1 = exp2f((v1 - m) * 1.44269504f);
                float p2 = (r0 < 8) ? exp2f((v2 - m) * 1.44269504f) : 0.f;
                float s = p0 + p1 + p2;
                s += __shfl_xor(s, 1); s += __shfl_xor(s, 2);
                s += __shfl_xor(s, 4); s += __shfl_xor(s, 8);
                float inv = 1.0f / s;
                const int fr = ft * 16 + 4 * kg + r;
                Ph[fr * RS +      r0] = f2bf(p0 * inv);
                Ph[fr * RS + 16 + r0] = f2bf(p1 * inv);
                Ph[fr * RS + 32 + r0] = f2bf(p2 * inv);
            }
        };
        p2unit(w);
        if (w < 2) p2unit(w + 4);
        __syncthreads();   // B2: P ready

        // ================= P3: O = P @ V + res, relu  (MFMA, C-init = res) =================
        const int h = w >> 1;
        const ushort* Ph = &sCur[h][0];
        bf16x8 vb0 = *(const bf16x8*)&sVT[ec * RS + kg * 8];        // B[k=g][n=d]: vT[ec][g]
        bf16x8 vb1 = *(const bf16x8*)&sVT[ec * RS + 32 + kg * 8];
        float vo0[4], vo1[4], vo2[4];
        #pragma unroll
        for (int ft = 0; ft < 3; ++ft) {
            bf16x8 pa0 = *(const bf16x8*)&Ph[(ft * 16 + r0) * RS + kg * 8];
            bf16x8 pa1 = *(const bf16x8*)&Ph[(ft * 16 + r0) * RS + 32 + kg * 8];
            f32x4 o = (ft == 0) ? res0 : (ft == 1) ? res1 : res2;
            o = MFMA(pa0, vb0, o);
            o = MFMA(pa1, vb1, o);
            #pragma unroll
            for (int r = 0; r < 4; ++r) {
                float v = fmaxf(o[r], 0.f);
                if (ft == 0) vo0[r] = v; else if (ft == 1) vo1[r] = v; else vo2[r] = v;
            }
        }

        // ================= P4: LayerNorm over e (cross-wave via sRed) =================
        #pragma unroll
        for (int ft = 0; ft < 3; ++ft) {
            #pragma unroll
            for (int r = 0; r < 4; ++r) {
                float v = (ft == 0) ? vo0[r] : (ft == 1) ? vo1[r] : vo2[r];
                float a = v, b = v * v;
                a += __shfl_xor(a, 1); b += __shfl_xor(b, 1);
                a += __shfl_xor(a, 2); b += __shfl_xor(b, 2);
                a += __shfl_xor(a, 4); b += __shfl_xor(b, 4);
                a += __shfl_xor(a, 8); b += __shfl_xor(b, 8);
                if (r0 == 0) {
                    const int fr = ft * 16 + 4 * kg + r;
                    sRed[0][w][fr] = a;
                    sRed[1][w][fr] = b;
                }
            }
        }
        __syncthreads();   // B3: partials ready

        #pragma unroll
        for (int ft = 0; ft < 3; ++ft) {
            #pragma unroll
            for (int r = 0; r < 4; ++r) {
                const int fr = ft * 16 + 4 * kg + r;
                float v  = (ft == 0) ? vo0[r] : (ft == 1) ? vo1[r] : vo2[r];
                float s1 = sRed[0][0][fr] + sRed[0][1][fr] + sRed[0][2][fr] + sRed[0][3][fr];
                float s2 = sRed[1][0][fr] + sRed[1][1][fr] + sRed[1][2][fr] + sRed[1][3][fr];
                float mu  = s1 * 0.015625f;
                float var = fmaf(s2, 0.015625f, -mu * mu);
                float yv  = (v - mu) * rsqrtf(var + 1e-3f) * gV + btV;
                if (fr < TF) {
                    if (lay == 0) {
                        ushort hh = f2bf(yv);
                        sCur[0][fr * RS + ec] = hh;
                        sCur[1][fr * RS + ec] = f2bf(yv - bf2f(hh));
                    } else {
                        out[base + fr * TE + ec] = yv;
                    }
                }
            }
        }
        __syncthreads();   // B4: next-layer cur ready / final
    }
}

extern "C" void kernel_launch(void* const* d_in, const int* in_sizes, int n_in,
                              void* d_out, int out_size, void* d_ws, size_t ws_size,
                              hipStream_t stream) {
    const float* x     = (const float*)d_in[0];
    const float* Wq    = (const float*)d_in[1];
    const float* bq    = (const float*)d_in[2];
    const float* Wk    = (const float*)d_in[3];
    const float* bk    = (const float*)d_in[4];
    const float* Wv    = (const float*)d_in[5];
    const float* bv    = (const float*)d_in[6];
    const float* Wr    = (const float*)d_in[7];
    const float* br    = (const float*)d_in[8];
    const float* gamma = (const float*)d_in[9];
    const float* beta  = (const float*)d_in[10];
    float* outp = (float*)d_out;
    ushort* wsf = (ushort*)d_ws;    // 32 KiB of W B-fragments

    prep_wfrags<<<64, 256, 0, stream>>>(Wq, Wk, Wv, Wr, wsf);

    const int B = in_sizes[0] / (TF * TE);
    autoint_mfma<<<B, NTH, 0, stream>>>(x, bq, bk, bv, br, gamma, beta, wsf, outp);
}

// Round 5
// 749.069 us; speedup vs baseline: 7.8838x; 1.1036x over previous
//
#include <hip/hip_runtime.h>

#define TF 40
#define TE 64
#define NTH 256

// ---- LDS pool (ushort element offsets) ----
// [cur 48x72 (aliased by P0 48x48)][P1 48x48][Q 40x72][K 40x72][VT 64x48]
// Q/K row-40..47 *reads* spill into the next buffer (finite bf16, results masked);
// VT/P reads never go OOB (kg>=2 fragment loads are skipped and reg-zeroed).
#define RSC 72           // cur/Q/K row stride (144B: 16B-aligned, bank-stride 4 -> 2-way free)
#define RSP 48           // P/VT row stride (96B: 16B-aligned)
#define OFF_CUR 0
#define OFF_P1  3456
#define OFF_Q   5760
#define OFF_K   8640
#define OFF_VT  11520
#define POOLSZ  14592    // 29184 B + sRed 1280 B = 30464 B -> 5 blocks/CU

typedef __attribute__((ext_vector_type(8))) short bf16x8;
typedef __attribute__((ext_vector_type(4))) float f32x4;
typedef unsigned int uint;
typedef unsigned short ushort;

#define MFMA(a, b, c) __builtin_amdgcn_mfma_f32_16x16x32_bf16(a, b, c, 0, 0, 0)

__device__ __forceinline__ uint cvtpk(float a, float b) {   // lo=bf16(a), hi=bf16(b), RNE
    uint r; asm("v_cvt_pk_bf16_f32 %0, %1, %2" : "=v"(r) : "v"(a), "v"(b)); return r;
}
__device__ __forceinline__ ushort f2bf(float x) {           // prep-kernel only (cold)
    union { float f; uint u; } a; a.f = x;
    uint r = a.u + 0x7FFFu + ((a.u >> 16) & 1u);
    return (ushort)(r >> 16);
}

// ---- prep: pre-swizzle W into MFMA B-fragment order in d_ws (unchanged layout) ----
// frag_id = ((mat*2 + k2)*4 + etile); elem = frag_id*512 + lane*8 + j
// value   = W[k2*32 + (lane>>4)*8 + j][etile*16 + (lane&15)]
__global__ void prep_wfrags(const float* __restrict__ Wq, const float* __restrict__ Wk,
                            const float* __restrict__ Wv, const float* __restrict__ Wr,
                            ushort* __restrict__ wsf) {
    int idx = blockIdx.x * blockDim.x + threadIdx.x;   // 16384
    int j    = idx & 7;
    int lane = (idx >> 3) & 63;
    int et   = (idx >> 9) & 3;
    int k2   = (idx >> 11) & 1;
    int mat  = (idx >> 12) & 3;
    const float* W = (mat == 0) ? Wq : (mat == 1) ? Wk : (mat == 2) ? Wv : Wr;
    wsf[idx] = f2bf(W[(k2 * 32 + (lane >> 4) * 8 + j) * TE + et * 16 + (lane & 15)]);
}

__global__ __launch_bounds__(NTH)
void autoint_mfma(const float* __restrict__ x,
                  const float* __restrict__ bq, const float* __restrict__ bk,
                  const float* __restrict__ bv, const float* __restrict__ br,
                  const float* __restrict__ gamma, const float* __restrict__ beta,
                  const ushort* __restrict__ wsf,
                  float* __restrict__ out) {
    __shared__ ushort pool[POOLSZ];
    __shared__ float  sRed[4][TF][2];   // [wave][f][sum,sumsq]

    const int t  = threadIdx.x;
    const int w  = t >> 6;             // wave = output e-tile
    const int l  = t & 63;
    const int r0 = l & 15;
    const int kg = l >> 4;
    const int ec = 16 * w + r0;        // C-frag column
    const size_t base = (size_t)blockIdx.x * (TF * TE);

    const float bQ = bq[ec], bK = bk[ec], bV = bv[ec], bR = br[ec];
    const float gV = gamma[ec], btV = beta[ec];

    // W B-fragments: 8 x bf16x8 (32 VGPR), loaded once, reused both layers
    const bf16x8* wsv = (const bf16x8*)wsf;
    const bf16x8 wq0 = wsv[(0*4 + w)*64 + l], wq1 = wsv[(1*4 + w)*64 + l];
    const bf16x8 wk0 = wsv[(2*4 + w)*64 + l], wk1 = wsv[(3*4 + w)*64 + l];
    const bf16x8 wv0 = wsv[(4*4 + w)*64 + l], wv1 = wsv[(5*4 + w)*64 + l];
    const bf16x8 wr0 = wsv[(6*4 + w)*64 + l], wr1 = wsv[(7*4 + w)*64 + l];

    // ---- load x -> cur (bf16, cvt_pk pairs); zero pad rows 40..47 ----
    {
        const float4* xb4 = (const float4*)(x + base);
        for (int i = t; i < TF * TE / 4; i += NTH) {
            float4 xv = xb4[i];
            int f = i >> 4, c = (i & 15) << 2;
            uint2 ph; ph.x = cvtpk(xv.x, xv.y); ph.y = cvtpk(xv.z, xv.w);
            *(uint2*)&pool[OFF_CUR + f * RSC + c] = ph;
        }
        for (int i = t; i < 288; i += NTH) ((uint*)pool)[1440 + i] = 0u;  // rows 40..47
    }
    __syncthreads();   // B0

    for (int lay = 0; lay < 2; ++lay) {
        // ========== P1: q,k,v,res = relu(cur @ W + b) ==========
        f32x4 res0, res1, res2;
        #pragma unroll
        for (int ft = 0; ft < 3; ++ft) {
            const int rowb = (ft * 16 + r0) * RSC + kg * 8;
            bf16x8 a0 = *(const bf16x8*)&pool[OFF_CUR + rowb];
            bf16x8 a1 = *(const bf16x8*)&pool[OFF_CUR + rowb + 32];
            f32x4 z = {0.f, 0.f, 0.f, 0.f};
            f32x4 aq = z, ak = z, av = z, ar = z;
            aq = MFMA(a0, wq0, aq); aq = MFMA(a1, wq1, aq);
            ak = MFMA(a0, wk0, ak); ak = MFMA(a1, wk1, ak);
            av = MFMA(a0, wv0, av); av = MFMA(a1, wv1, av);
            ar = MFMA(a0, wr0, ar); ar = MFMA(a1, wr1, ar);
            const int fb = ft * 16 + 4 * kg;         // C-frag rows fb..fb+3, col ec
            if (fb < TF) {                           // q,k rows 40..47 never written
                uint q01 = cvtpk(fmaxf(aq[0]+bQ,0.f), fmaxf(aq[1]+bQ,0.f));
                uint q23 = cvtpk(fmaxf(aq[2]+bQ,0.f), fmaxf(aq[3]+bQ,0.f));
                pool[OFF_Q + (fb+0)*RSC + ec] = (ushort)q01;
                pool[OFF_Q + (fb+1)*RSC + ec] = (ushort)(q01 >> 16);
                pool[OFF_Q + (fb+2)*RSC + ec] = (ushort)q23;
                pool[OFF_Q + (fb+3)*RSC + ec] = (ushort)(q23 >> 16);
                uint k01 = cvtpk(fmaxf(ak[0]+bK,0.f), fmaxf(ak[1]+bK,0.f));
                uint k23 = cvtpk(fmaxf(ak[2]+bK,0.f), fmaxf(ak[3]+bK,0.f));
                pool[OFF_K + (fb+0)*RSC + ec] = (ushort)k01;
                pool[OFF_K + (fb+1)*RSC + ec] = (ushort)(k01 >> 16);
                pool[OFF_K + (fb+2)*RSC + ec] = (ushort)k23;
                pool[OFF_K + (fb+3)*RSC + ec] = (ushort)(k23 >> 16);
            }
            // vT always written (pad cols stay finite; they multiply exact-zero P)
            uint2 pv;
            pv.x = cvtpk(fmaxf(av[0]+bV,0.f), fmaxf(av[1]+bV,0.f));
            pv.y = cvtpk(fmaxf(av[2]+bV,0.f), fmaxf(av[3]+bV,0.f));
            *(uint2*)&pool[OFF_VT + ec * RSP + fb] = pv;
            f32x4 rr = {fmaxf(ar[0]+bR,0.f), fmaxf(ar[1]+bR,0.f),
                        fmaxf(ar[2]+bR,0.f), fmaxf(ar[3]+bR,0.f)};
            if (ft == 0) res0 = rr; else if (ft == 1) res1 = rr; else res2 = rr;
        }
        __syncthreads();   // B1: q/k/vT ready; cur A-reads done -> P0 may overwrite

        // ========== P2: S = q k^T / sqrt(32), softmax -> P (bf16) ==========
        auto p2unit = [&](int u) {
            const int h  = (u >= 3) ? 1 : 0;
            const int ft = u - 3 * h;
            const int co = 32 * h + kg * 8;
            bf16x8 a  = *(const bf16x8*)&pool[OFF_Q + (ft * 16 + r0) * RSC + co];
            bf16x8 b0 = *(const bf16x8*)&pool[OFF_K + (r0) * RSC + co];
            bf16x8 b1 = *(const bf16x8*)&pool[OFF_K + (16 + r0) * RSC + co];
            bf16x8 b2 = *(const bf16x8*)&pool[OFF_K + (32 + r0) * RSC + co];  // r0>=8 spills -> masked
            f32x4 z = {0.f, 0.f, 0.f, 0.f};
            f32x4 c0 = MFMA(a, b0, z);
            f32x4 c1 = MFMA(a, b1, z);
            f32x4 c2 = MFMA(a, b2, z);
            ushort* Ph = pool + (h ? OFF_P1 : OFF_CUR);
            #pragma unroll
            for (int r = 0; r < 4; ++r) {
                const float SC = 0.17677669529663687f;
                float v0 = c0[r] * SC, v1 = c1[r] * SC;
                float v2 = (r0 < 8) ? c2[r] * SC : -3.0e38f;   // S cols 40..47 masked
                float m = fmaxf(fmaxf(v0, v1), v2);
                m = fmaxf(m, __shfl_xor(m, 1)); m = fmaxf(m, __shfl_xor(m, 2));
                m = fmaxf(m, __shfl_xor(m, 4)); m = fmaxf(m, __shfl_xor(m, 8));
                const float LOG2E = 1.44269504f;
                float p0 = __builtin_amdgcn_exp2f((v0 - m) * LOG2E);
                float p1 = __builtin_amdgcn_exp2f((v1 - m) * LOG2E);
                float p2v = (r0 < 8) ? __builtin_amdgcn_exp2f((v2 - m) * LOG2E) : 0.f;
                float s = p0 + p1 + p2v;
                s += __shfl_xor(s, 1); s += __shfl_xor(s, 2);
                s += __shfl_xor(s, 4); s += __shfl_xor(s, 8);
                float inv = 1.0f / s;
                const int fr = ft * 16 + 4 * kg + r;
                uint p01 = cvtpk(p0 * inv, p1 * inv);
                uint p22 = cvtpk(p2v * inv, p2v * inv);
                Ph[fr * RSP +      r0] = (ushort)p01;
                Ph[fr * RSP + 16 + r0] = (ushort)(p01 >> 16);
                Ph[fr * RSP + 32 + r0] = (ushort)p22;        // cols 40..47 exact zero
            }
        };
        p2unit(w);
        if (w < 2) p2unit(w + 4);
        __syncthreads();   // B2: P ready

        // ========== P3: O = P @ V + res, relu (k=48: kg>=2 frags reg-zeroed) ==========
        const int hh = w >> 1;
        const ushort* Ph = pool + (hh ? OFF_P1 : OFF_CUR);
        const bf16x8 zz = {0,0,0,0,0,0,0,0};
        bf16x8 vb0 = *(const bf16x8*)&pool[OFF_VT + ec * RSP + kg * 8];
        bf16x8 vb1 = zz;
        if (kg < 2) vb1 = *(const bf16x8*)&pool[OFF_VT + ec * RSP + 32 + kg * 8];
        float vo0[4], vo1[4], vo2[4];
        #pragma unroll
        for (int ft = 0; ft < 3; ++ft) {
            bf16x8 pa0 = *(const bf16x8*)&Ph[(ft * 16 + r0) * RSP + kg * 8];
            bf16x8 pa1 = zz;
            if (kg < 2) pa1 = *(const bf16x8*)&Ph[(ft * 16 + r0) * RSP + 32 + kg * 8];
            f32x4 o = (ft == 0) ? res0 : (ft == 1) ? res1 : res2;
            o = MFMA(pa0, vb0, o);
            o = MFMA(pa1, vb1, o);
            #pragma unroll
            for (int r = 0; r < 4; ++r) {
                float v = fmaxf(o[r], 0.f);
                if (ft == 0) vo0[r] = v; else if (ft == 1) vo1[r] = v; else vo2[r] = v;
            }
        }

        // ========== P4: LayerNorm over e (cross-wave partials, float2-packed) ==========
        #pragma unroll
        for (int ft = 0; ft < 3; ++ft) {
            const int fb = ft * 16 + 4 * kg;
            if (fb < TF) {                                 // rows 40..47: skip entirely
                #pragma unroll
                for (int r = 0; r < 4; ++r) {
                    float v = (ft == 0) ? vo0[r] : (ft == 1) ? vo1[r] : vo2[r];
                    float a = v, b = v * v;
                    a += __shfl_xor(a, 1); b += __shfl_xor(b, 1);
                    a += __shfl_xor(a, 2); b += __shfl_xor(b, 2);
                    a += __shfl_xor(a, 4); b += __shfl_xor(b, 4);
                    a += __shfl_xor(a, 8); b += __shfl_xor(b, 8);
                    if (r0 == 0) *(float2*)&sRed[w][fb + r][0] = make_float2(a, b);
                }
            }
        }
        __syncthreads();   // B3: partials ready (also orders P-reads < cur-writes)

        #pragma unroll
        for (int ft = 0; ft < 3; ++ft) {
            const int fb = ft * 16 + 4 * kg;
            if (fb < TF) {
                float y[4];
                #pragma unroll
                for (int r = 0; r < 4; ++r) {
                    const int fr = fb + r;
                    float s1 = 0.f, s2 = 0.f;
                    #pragma unroll
                    for (int ww = 0; ww < 4; ++ww) {
                        float2 p = *(const float2*)&sRed[ww][fr][0];
                        s1 += p.x; s2 += p.y;
                    }
                    float v   = (ft == 0) ? vo0[r] : (ft == 1) ? vo1[r] : vo2[r];
                    float mu  = s1 * 0.015625f;
                    float var = fmaf(s2, 0.015625f, -mu * mu);
                    y[r] = (v - mu) * rsqrtf(var + 1e-3f) * gV + btV;
                }
                if (lay == 0) {
                    uint c01 = cvtpk(y[0], y[1]), c23 = cvtpk(y[2], y[3]);
                    pool[OFF_CUR + (fb + 0) * RSC + ec] = (ushort)c01;
                    pool[OFF_CUR + (fb + 1) * RSC + ec] = (ushort)(c01 >> 16);
                    pool[OFF_CUR + (fb + 2) * RSC + ec] = (ushort)c23;
                    pool[OFF_CUR + (fb + 3) * RSC + ec] = (ushort)(c23 >> 16);
                } else {
                    #pragma unroll
                    for (int r = 0; r < 4; ++r)
                        out[base + (fb + r) * TE + ec] = y[r];
                }
            }
        }
        if (lay == 0) __syncthreads();   // B4: next-layer cur ready
    }
}

extern "C" void kernel_launch(void* const* d_in, const int* in_sizes, int n_in,
                              void* d_out, int out_size, void* d_ws, size_t ws_size,
                              hipStream_t stream) {
    const float* x     = (const float*)d_in[0];
    const float* Wq    = (const float*)d_in[1];
    const float* bq    = (const float*)d_in[2];
    const float* Wk    = (const float*)d_in[3];
    const float* bk    = (const float*)d_in[4];
    const float* Wv    = (const float*)d_in[5];
    const float* bv    = (const float*)d_in[6];
    const float* Wr    = (const float*)d_in[7];
    const float* br    = (const float*)d_in[8];
    const float* gamma = (const float*)d_in[9];
    const float* beta  = (const float*)d_in[10];
    float* outp = (float*)d_out;
    ushort* wsf = (ushort*)d_ws;   // 32 KiB W B-fragments

    prep_wfrags<<<64, 256, 0, stream>>>(Wq, Wk, Wv, Wr, wsf);

    const int B = in_sizes[0] / (TF * TE);
    autoint_mfma<<<B, NTH, 0, stream>>>(x, bq, bk, bv, br, gamma, beta, wsf, outp);
}